// Round 1
// baseline (2835.756 us; speedup 1.0000x reference)
//
#include <hip/hip_runtime.h>
#include <stddef.h>

// ---------- types / helpers ----------
using short8 = __attribute__((ext_vector_type(8))) short;
using f32x4  = __attribute__((ext_vector_type(4))) float;
using u16x4  = __attribute__((ext_vector_type(4))) unsigned short;

__device__ __forceinline__ unsigned short cvt_bf16(float f) {
    unsigned u = __builtin_bit_cast(unsigned, f);
    u += 0x7fffu + ((u >> 16) & 1u);          // RNE
    return (unsigned short)(u >> 16);
}

__device__ __forceinline__ void gload_lds16(const void* g, void* l) {
    __builtin_amdgcn_global_load_lds(
        (const __attribute__((address_space(1))) unsigned*)g,
        (__attribute__((address_space(3))) unsigned*)l, 16, 0, 0);
}

#define MFMA16(a, b, c) __builtin_amdgcn_mfma_f32_16x16x32_bf16((a), (b), (c), 0, 0, 0)

// B=128, T=256, I=H=K=1024
// ---------- weight conversion: f32 -> bf16 ----------
__global__ __launch_bounds__(256) void convert_w(const float* __restrict__ Wi,
                                                 const float* __restrict__ Wh,
                                                 unsigned short* __restrict__ Wib,
                                                 unsigned short* __restrict__ Whb) {
    const float* src = blockIdx.y ? Wh : Wi;
    unsigned short* dst = blockIdx.y ? Whb : Wib;
    int base = blockIdx.x * 2048 + threadIdx.x * 8;
#pragma unroll
    for (int c = 0; c < 2; ++c) {
        float4 v = *(const float4*)(src + base + c * 4);
        u16x4 o;
        o.x = cvt_bf16(v.x); o.y = cvt_bf16(v.y); o.z = cvt_bf16(v.z); o.w = cvt_bf16(v.w);
        *(u16x4*)(dst + base + c * 4) = o;
    }
}

// ---------- h init: hidden f32 [2][128][1024] -> bf16 [256][1024] ----------
__global__ __launch_bounds__(256) void init_h(const float* __restrict__ hidden,
                                              unsigned short* __restrict__ h0) {
    int row = blockIdx.x;
    int tid = threadIdx.x;
    float4 v = *(const float4*)(hidden + (size_t)row * 1024 + tid * 4);
    u16x4 o;
    o.x = cvt_bf16(v.x); o.y = cvt_bf16(v.y); o.z = cvt_bf16(v.z); o.w = cvt_bf16(v.w);
    *(u16x4*)(h0 + (size_t)row * 1024 + tid * 4) = o;
}

// ---------- pre-GEMM: pre[t][b][n] = sum_k x[b][t][k] * Wi[n][k] + bi[n] ----------
// tile 128x128 (one t per M-tile), BK=64, 4 waves of 64x64, A reg-staged f32->bf16, B via global_load_lds
__global__ __launch_bounds__(256) void pre_gemm(const float* __restrict__ x,
                                                const unsigned short* __restrict__ Wib,
                                                const float* __restrict__ bi,
                                                float* __restrict__ pre) {
    __shared__ unsigned short Alds[128 * 64];
    __shared__ unsigned short Blds[128 * 64];
    const int tid  = threadIdx.x;
    const int lane = tid & 63, wid = tid >> 6;
    const int wr = wid >> 1, wc = wid & 1;     // 2x2 waves, 64x64 each
    const int t  = blockIdx.y;                 // time index == M-tile
    const int n0 = blockIdx.x * 128;

    f32x4 acc[4][4] = {};

    for (int kt = 0; kt < 16; ++kt) {
        const int k0 = kt * 64;
        __syncthreads();
        // A: 128 rows (batch) x 64 cols f32 -> bf16 in LDS
#pragma unroll
        for (int c = 0; c < 8; ++c) {
            int flat = c * 256 + tid;          // 0..2047
            int row = flat >> 4;               // 0..127  (batch b)
            int seg = flat & 15;               // 16 segs of 4 f32
            float4 v = *(const float4*)(x + (size_t)row * 262144 + (size_t)t * 1024 + k0 + seg * 4);
            u16x4 h;
            h.x = cvt_bf16(v.x); h.y = cvt_bf16(v.y); h.z = cvt_bf16(v.z); h.w = cvt_bf16(v.w);
            *(u16x4*)&Alds[row * 64 + seg * 4] = h;
        }
        // B: 128 rows (n) x 64 cols bf16 direct to LDS
#pragma unroll
        for (int c = 0; c < 4; ++c) {
            int flat = c * 256 + tid;          // 0..1023
            int row = flat >> 3;               // 0..127
            int seg = flat & 7;                // 8 segs of 8 bf16
            gload_lds16(Wib + (size_t)(n0 + row) * 1024 + k0 + seg * 8, &Blds[flat * 8]);
        }
        __syncthreads();
#pragma unroll
        for (int ks = 0; ks < 2; ++ks) {
            short8 a[4], b[4];
#pragma unroll
            for (int i = 0; i < 4; ++i)
                a[i] = *(const short8*)&Alds[(wr * 64 + i * 16 + (lane & 15)) * 64 + ks * 32 + (lane >> 4) * 8];
#pragma unroll
            for (int j = 0; j < 4; ++j)
                b[j] = *(const short8*)&Blds[(wc * 64 + j * 16 + (lane & 15)) * 64 + ks * 32 + (lane >> 4) * 8];
#pragma unroll
            for (int i = 0; i < 4; ++i)
#pragma unroll
                for (int j = 0; j < 4; ++j)
                    acc[i][j] = MFMA16(a[i], b[j], acc[i][j]);
        }
    }
    // epilogue: add bi, store f32 pre[t][b][n]
    const int rbase = wr * 64 + (lane >> 4) * 4;
    const int cbase = n0 + wc * 64 + (lane & 15);
#pragma unroll
    for (int i = 0; i < 4; ++i) {
#pragma unroll
        for (int j = 0; j < 4; ++j) {
            int n = cbase + j * 16;
            float bv = bi[n];
#pragma unroll
            for (int r = 0; r < 4; ++r) {
                int m = rbase + i * 16 + r;    // batch b
                pre[((size_t)t * 128 + m) * 1024 + n] = acc[i][j][r] + bv;
            }
        }
    }
}

// ---------- one recurrence step (fwd rows 0..127, bwd rows 128..255) ----------
// C[256x1024] = h_in @ Wh^T ; h_next = softplus5(C + pre + bh); scatter to out + h_out
// tile 32x32, BK=256, 4 waves of 16x16, 256 blocks
__global__ __launch_bounds__(256) void rnn_step(const unsigned short* __restrict__ hin,
                                                unsigned short* __restrict__ hout,
                                                const unsigned short* __restrict__ Whb,
                                                const float* __restrict__ pre,
                                                const float* __restrict__ bh,
                                                float* __restrict__ out,
                                                int s) {
    __shared__ unsigned short Alds[32 * 256];
    __shared__ unsigned short Blds[32 * 256];
    const int tid  = threadIdx.x;
    const int lane = tid & 63, wid = tid >> 6;
    const int wr = wid >> 1, wc = wid & 1;     // 2x2 waves, 16x16 each
    const int m0 = blockIdx.y * 32;            // rows (0..255)
    const int n0 = blockIdx.x * 32;            // cols (0..1023)

    f32x4 acc = {};

    for (int kt = 0; kt < 4; ++kt) {
        const int k0 = kt * 256;
        __syncthreads();
#pragma unroll
        for (int c = 0; c < 4; ++c) {          // A: 32 x 256 bf16
            int flat = c * 256 + tid;          // 0..1023
            int row = flat >> 5;               // 0..31
            int seg = flat & 31;               // 32 segs of 8 bf16
            gload_lds16(hin + (size_t)(m0 + row) * 1024 + k0 + seg * 8, &Alds[flat * 8]);
        }
#pragma unroll
        for (int c = 0; c < 4; ++c) {          // B: 32 x 256 bf16
            int flat = c * 256 + tid;
            int row = flat >> 5;
            int seg = flat & 31;
            gload_lds16(Whb + (size_t)(n0 + row) * 1024 + k0 + seg * 8, &Blds[flat * 8]);
        }
        __syncthreads();
#pragma unroll
        for (int ks = 0; ks < 8; ++ks) {
            short8 a = *(const short8*)&Alds[(wr * 16 + (lane & 15)) * 256 + ks * 32 + (lane >> 4) * 8];
            short8 b = *(const short8*)&Blds[(wc * 16 + (lane & 15)) * 256 + ks * 32 + (lane >> 4) * 8];
            acc = MFMA16(a, b, acc);
        }
    }

    // epilogue
    const int mloc = wr * 16 + (lane >> 4) * 4;
    const int n = n0 + wc * 16 + (lane & 15);
    const float bhv = bh[n];
#pragma unroll
    for (int r = 0; r < 4; ++r) {
        int m = m0 + mloc + r;                 // 0..255
        int b = m & 127;
        bool isfwd = (m < 128);
        int prow = isfwd ? s : (255 - s);
        float v = acc[r] + pre[((size_t)prow * 128 + b) * 1024 + n] + bhv;
        float hv = (5.0f * v > 20.0f) ? v : 0.2f * log1pf(__expf(5.0f * v));
        hout[(size_t)m * 1024 + n] = cvt_bf16(hv);
        int tout = isfwd ? ((239 - s + 256) & 255) : s;
        int c    = isfwd ? n : (1024 + n);
        out[(size_t)b * 524288 + (size_t)tout * 2048 + c] = hv;
    }
}

// ---------- launch ----------
extern "C" void kernel_launch(void* const* d_in, const int* in_sizes, int n_in,
                              void* d_out, int out_size, void* d_ws, size_t ws_size,
                              hipStream_t stream) {
    const float* x      = (const float*)d_in[0];
    const float* hidden = (const float*)d_in[1];
    const float* Wi     = (const float*)d_in[2];
    const float* bi     = (const float*)d_in[3];
    const float* Wh     = (const float*)d_in[4];
    const float* bh     = (const float*)d_in[5];
    float* out = (float*)d_out;

    char* ws = (char*)d_ws;
    float*          pre = (float*)ws;                               // 128 MB
    unsigned short* Wib = (unsigned short*)(ws + 134217728);        // 2 MB
    unsigned short* Whb = (unsigned short*)(ws + 136314880);        // 2 MB
    unsigned short* h0  = (unsigned short*)(ws + 138412032);        // 512 KB
    unsigned short* h1  = (unsigned short*)(ws + 138936320);        // 512 KB

    convert_w<<<dim3(512, 2), 256, 0, stream>>>(Wi, Wh, Wib, Whb);
    init_h<<<256, 256, 0, stream>>>(hidden, h0);
    pre_gemm<<<dim3(8, 256), 256, 0, stream>>>(x, Wib, bi, pre);

    for (int s = 0; s < 256; ++s) {
        const unsigned short* hi = (s & 1) ? h1 : h0;
        unsigned short*       ho = (s & 1) ? h0 : h1;
        rnn_step<<<dim3(32, 8), 256, 0, stream>>>(hi, ho, Whb, pre, bh, out, s);
    }
}